// Round 4
// baseline (10810.981 us; speedup 1.0000x reference)
//
#include <hip/hip_runtime.h>
#include <hip/hip_bf16.h>
#include <cstdint>
#include <cstddef>

// Problem constants
#define T_LEN 1024
#define B_SZ  64
#define H_DIM 512
#define D_IN  512

// Decomposition: 2 layers x 2 dirs x 4 batch-groups (16 rows) x 32 col-groups (16 cols)
#define NBG    4
#define GROUP  32          // blocks per (layer,dir,bg) sync group
#define BS     16          // batch rows per group
#define CW     16          // h-cols per block

typedef __attribute__((ext_vector_type(8))) short short8;
typedef __attribute__((ext_vector_type(4))) float f32x4;
typedef unsigned long long ull;

// LDS layout (bytes): Whh 3x16KB + H 16KB + D 5KB = 70656 -> 2 blocks/CU
#define OFF_WHH  0
#define OFF_H    49152
#define OFF_D    65536
#define SMEM_BYTES 70656

__device__ __forceinline__ int swz(int row, int byteoff) {
  // XOR-swizzle 16B granules within a row (breaks stride-1024 bank conflicts).
  return byteoff ^ ((row & 7) << 4);
}

__device__ __forceinline__ unsigned short f2bf(float f) {
  unsigned u = __float_as_uint(f);
  return (unsigned short)((u + 0x7FFFu + ((u >> 16) & 1u)) >> 16);   // RNE
}

__device__ __forceinline__ short8 pack8(float4 a, float4 b) {
  short8 v;
  v[0] = (short)f2bf(a.x); v[1] = (short)f2bf(a.y);
  v[2] = (short)f2bf(a.z); v[3] = (short)f2bf(a.w);
  v[4] = (short)f2bf(b.x); v[5] = (short)f2bf(b.y);
  v[6] = (short)f2bf(b.z); v[7] = (short)f2bf(b.w);
  return v;
}

__device__ __forceinline__ unsigned cvtpk(float lo, float hi) {
  unsigned r;
  asm("v_cvt_pk_bf16_f32 %0, %1, %2" : "=v"(r) : "v"(lo), "v"(hi));   // RNE
  return r;
}
__device__ __forceinline__ short8 cvtpk8(float4 a, float4 b) {
  union { unsigned u[4]; short8 s; } cv;
  cv.u[0] = cvtpk(a.x, a.y); cv.u[1] = cvtpk(a.z, a.w);
  cv.u[2] = cvtpk(b.x, b.y); cv.u[3] = cvtpk(b.z, b.w);
  return cv.s;
}

__device__ __forceinline__ float sigm(float x) { return 1.0f / (1.0f + __expf(-x)); }
__device__ __forceinline__ float fast_tanh(float x) { return 1.0f - 2.0f / (__expf(2.0f * x) + 1.0f); }

__device__ __forceinline__ size_t hidx(int layer, int par, int dir, int bg, int row, int col) {
  const int g = ((layer * 2 + par) * 2 + dir) * NBG + bg;   // 0..31
  return ((size_t)g * BS + row) * H_DIM + col;              // 512KB total (bf16)
}

__global__ __launch_bounds__(256, 2)
void gru_fused(const float* __restrict__ x,
               const float* __restrict__ enc,
               const float* __restrict__ WihF, const float* __restrict__ WhhF,
               const float* __restrict__ bihF, const float* __restrict__ bhhF,
               const float* __restrict__ WihB, const float* __restrict__ WhhB,
               const float* __restrict__ bihB, const float* __restrict__ bhhB,
               float* dout,
               unsigned* __restrict__ flags,
               unsigned short* __restrict__ hbuf)
{
  __shared__ alignas(16) char smem[SMEM_BYTES];

  const int bid   = blockIdx.x;
  const int layer = bid >> 8;        // 0..1
  const int lbid  = bid & 255;
  const int grp   = lbid & 7;        // dir*4+bg; same (mod 8) => same XCD round-robin
  const int dir   = grp >> 2;
  const int bg    = grp & 3;
  const int cg    = lbid >> 3;       // col-group 0..31
  const int tid   = threadIdx.x;
  const int wv    = tid >> 6;
  const int tb    = tid >> 4;        // 0..15 batch-local row / staging row
  const int tc    = tid & 15;        // 0..15 col-local / staging segment
  const int lrow  = tc;              // MFMA fragment row (= lane&15)
  const int q     = tb & 3;          // MFMA k-quarter (= lane>>4)
  const int hc0   = cg * CW;
  const int hcol  = hc0 + tc;
  const int bglobal = bg * BS + tb;
  const int dircol  = dir * H_DIM;

  const float* Wih = (dir ? WihB : WihF) + (size_t)layer * 3 * H_DIM * D_IN;
  const float* Whh = (dir ? WhhB : WhhF) + (size_t)layer * 3 * H_DIM * H_DIM;
  const float* bih = (dir ? bihB : bihF) + (size_t)layer * 3 * H_DIM;
  const float* bhh = (dir ? bhhB : bhhF) + (size_t)layer * 3 * H_DIM;

  unsigned* fl  = flags + (layer * 8 + grp) * 64;  // own group's 32 producer flags
  unsigned* fl0 = flags + grp * 64;                // layer-0 counterpart (for layer 1)

  // ---- Stage Whh into LDS (once): 3 gate tiles of 16 rows x 512 K bf16 ----
  #pragma unroll
  for (int g = 0; g < 3; ++g) {
    const float* s1 = Whh + (size_t)(g * H_DIM + hc0 + tb) * H_DIM + tc * 32;
    char* r1 = smem + OFF_WHH + g * 16384 + tb * 1024;
    #pragma unroll
    for (int u = 0; u < 4; ++u) {
      float4 a1 = ((const float4*)s1)[u * 2];
      float4 b1 = ((const float4*)s1)[u * 2 + 1];
      *(short8*)(r1 + swz(tb, tc * 64 + u * 16)) = pack8(a1, b1);
    }
  }

  // ---- Persistent Wih B-fragments in registers (time-invariant) ----
  short8 wfrag[16];
  if (wv < 3) {
    const float* bbase = Wih + (size_t)(wv * H_DIM + hc0 + lrow) * D_IN;
    #pragma unroll
    for (int kc = 0; kc < 16; ++kc) {
      const int k0 = kc * 32 + q * 8;
      float4 b0 = *(const float4*)(bbase + k0);
      float4 b1 = *(const float4*)(bbase + k0 + 4);
      wfrag[kc] = cvtpk8(b0, b1);
    }
  }

  // ---- Per-thread biases and initial hidden state ----
  const float b_r  = bih[hcol] + bhh[hcol];
  const float b_z  = bih[H_DIM + hcol] + bhh[H_DIM + hcol];
  const float b_xn = bih[2 * H_DIM + hcol];
  const float b_hn = bhh[2 * H_DIM + hcol];
  float hreg = enc[(size_t)layer * B_SZ * 2 * H_DIM + (size_t)bglobal * 2 * H_DIM + dircol + hcol];

  // ---- publish h0 (parity 0): packed 8B agent-scope stores, then flag=1 ----
  {
    unsigned v = f2bf(hreg);
    unsigned v1 = __shfl_down(v, 1);
    unsigned v2 = __shfl_down(v, 2);
    unsigned v3 = __shfl_down(v, 3);
    if ((tc & 3) == 0) {
      ull pk = (ull)v | ((ull)v1 << 16) | ((ull)v2 << 32) | ((ull)v3 << 48);
      __hip_atomic_store((ull*)&hbuf[hidx(layer, 0, dir, bg, tb, hcol)], pk,
                         __ATOMIC_RELAXED, __HIP_MEMORY_SCOPE_AGENT);
    }
  }
  asm volatile("s_waitcnt vmcnt(0)" ::: "memory");
  __syncthreads();   // also covers Whh LDS staging
  if (tid == 0)
    __hip_atomic_store(&fl[cg], 1u, __ATOMIC_RELAXED, __HIP_MEMORY_SCOPE_AGENT);

  // x-part of the gate pre-activations for one position, accumulated into am.
  // A-fragments direct from global (layer0: x, layer1: layer-0 y in dout),
  // B-fragments from persistent registers.
  auto xpart = [&](int pos, f32x4& am) {
    if (wv < 3) {
      const float* abase = (layer == 0)
        ? (x    + ((size_t)(bg * BS + lrow) * T_LEN + pos) * D_IN)
        : (dout + ((size_t)(bg * BS + lrow) * T_LEN + pos) * 2 * H_DIM + dircol);
      #pragma unroll
      for (int kc = 0; kc < 16; ++kc) {
        const int k0 = kc * 32 + q * 8;
        float4 a0 = *(const float4*)(abase + k0);
        float4 a1 = *(const float4*)(abase + k0 + 4);
        am = __builtin_amdgcn_mfma_f32_16x16x32_bf16(cvtpk8(a0, a1), wfrag[kc], am, 0, 0, 0);
      }
    }
  };

  // ---- prologue: x-part for t=0 (layer 1 first waits for y0[p_0]) ----
  f32x4 acc_main = {0.f, 0.f, 0.f, 0.f};
  if (layer == 1) {
    if (tid < 32) {
      while (__hip_atomic_load(&fl0[tid], __ATOMIC_RELAXED, __HIP_MEMORY_SCOPE_AGENT) < 2u)
        __builtin_amdgcn_s_sleep(1);
    }
    __syncthreads();
  }
  xpart(dir ? (T_LEN - 1) : 0, acc_main);

  float yprev = 0.0f;

  for (int t = 0; t < T_LEN; ++t) {
    const int torig = dir ? (T_LEN - 1 - t) : t;

    // ---- main poll: all 32 of OUR group published h for this step ----
    if (tid < 32) {
      const unsigned tgt = (unsigned)(t + 1);
      while (__hip_atomic_load(&fl[tid], __ATOMIC_RELAXED, __HIP_MEMORY_SCOPE_AGENT) < tgt)
        __builtin_amdgcn_s_sleep(1);
    }
    __syncthreads();

    // ---- gather h_{t-1} (packed 8B agent-scope loads) ----
    ull hv[8];
    {
      const ull* hb = (const ull*)(hbuf + hidx(layer, t & 1, dir, bg, tb, 0) + tc * 32);
      #pragma unroll
      for (int u = 0; u < 8; ++u)
        hv[u] = __hip_atomic_load(hb + u, __ATOMIC_RELAXED, __HIP_MEMORY_SCOPE_AGENT);
    }
    // layer 1: delayed in-place overwrite of y0[t-1] with y1[t-1] (safe: own
    // flags >= t+1 imply every group member consumed y0 at that position)
    if (layer == 1 && t > 0) {
      const int tprev = dir ? (T_LEN - t) : (t - 1);
      dout[(size_t)bglobal * T_LEN * 2 * H_DIM + (size_t)tprev * 2 * H_DIM + dircol + hcol] = yprev;
    }
    {
      char* lh = smem + OFF_H + tb * 1024;
      #pragma unroll
      for (int u = 0; u < 4; ++u) {
        ull tmp[2] = {hv[u * 2], hv[u * 2 + 1]};
        *(short8*)(lh + swz(tb, tc * 64 + u * 16)) = *(const short8*)tmp;
      }
    }
    __syncthreads();

    // ---- on-chain h-part MFMAs: w0 r, w1 z (16 ch); w2 hn[0..7], w3 hn[8..15] ----
    f32x4 acc_hn = {0.f, 0.f, 0.f, 0.f};
    if (wv < 2) {
      char* wrow = smem + OFF_WHH + wv * 16384 + lrow * 1024;
      char* hr   = smem + OFF_H + lrow * 1024;
      #pragma unroll
      for (int kc = 0; kc < 16; ++kc) {
        short8 a = *(const short8*)(hr   + swz(lrow, kc * 64 + q * 16));
        short8 b = *(const short8*)(wrow + swz(lrow, kc * 64 + q * 16));
        acc_main = __builtin_amdgcn_mfma_f32_16x16x32_bf16(a, b, acc_main, 0, 0, 0);
      }
    } else {
      char* wrow = smem + OFF_WHH + 2 * 16384 + lrow * 1024;
      char* hr   = smem + OFF_H + lrow * 1024;
      const int k0 = (wv == 2) ? 0 : 8;
      #pragma unroll
      for (int kc = 0; kc < 8; ++kc) {
        short8 a = *(const short8*)(hr   + swz(lrow, (k0 + kc) * 64 + q * 16));
        short8 b = *(const short8*)(wrow + swz(lrow, (k0 + kc) * 64 + q * 16));
        acc_hn = __builtin_amdgcn_mfma_f32_16x16x32_bf16(a, b, acc_hn, 0, 0, 0);
      }
    }
    {
      if (wv < 3) {
        float* dt = (float*)(smem + OFF_D + wv * 1024);
        #pragma unroll
        for (int r = 0; r < 4; ++r)
          dt[(q * 4 + r) * 16 + ((lrow + 4 * q) & 15)] = acc_main[r];
      }
      if (wv >= 2) {
        float* dt = (float*)(smem + OFF_D + (wv + 1) * 1024);
        #pragma unroll
        for (int r = 0; r < 4; ++r)
          dt[(q * 4 + r) * 16 + ((lrow + 4 * q) & 15)] = acc_hn[r];
      }
    }
    __syncthreads();

    // ---- elementwise GRU update + immediate publish ----
    float hnew;
    {
      const float* Dr  = (const float*)(smem + OFF_D + 0 * 1024);
      const float* Dz  = (const float*)(smem + OFF_D + 1 * 1024);
      const float* Dxn = (const float*)(smem + OFF_D + 2 * 1024);
      const float* Dha = (const float*)(smem + OFF_D + 3 * 1024);
      const float* Dhb = (const float*)(smem + OFF_D + 4 * 1024);
      const int e = tb * 16 + ((tc + 4 * (tb >> 2)) & 15);
      const float r = sigm(Dr[e] + b_r);
      const float z = sigm(Dz[e] + b_z);
      const float n = fast_tanh(Dxn[e] + b_xn + r * (Dha[e] + Dhb[e] + b_hn));
      hnew = (1.0f - z) * n + z * hreg;
      hreg = hnew;

      // publish h_t to hbuf (packed 8B agent-scope stores)
      unsigned v = f2bf(hnew);
      unsigned v1 = __shfl_down(v, 1);
      unsigned v2 = __shfl_down(v, 2);
      unsigned v3 = __shfl_down(v, 3);
      if ((tc & 3) == 0) {
        ull pk = (ull)v | ((ull)v1 << 16) | ((ull)v2 << 32) | ((ull)v3 << 48);
        __hip_atomic_store((ull*)&hbuf[hidx(layer, (t + 1) & 1, dir, bg, tb, hcol)], pk,
                           __ATOMIC_RELAXED, __HIP_MEMORY_SCOPE_AGENT);
      }

      if (layer == 0) {
        // publish y0 to dout via coherent 8B stores (layer 1 reads it in-kernel)
        unsigned yv = __float_as_uint(hnew);
        unsigned yv1 = __shfl_down(yv, 1);
        if (!(tc & 1)) {
          ull pk = (ull)yv | ((ull)yv1 << 32);
          __hip_atomic_store((ull*)(dout + (size_t)bglobal * T_LEN * 2 * H_DIM
                                         + (size_t)torig * 2 * H_DIM + dircol + hcol),
                             pk, __ATOMIC_RELAXED, __HIP_MEMORY_SCOPE_AGENT);
        }
      } else {
        yprev = hnew;
      }
      if (t == T_LEN - 1) {
        dout[(size_t)B_SZ * T_LEN * 2 * H_DIM +
             ((size_t)layer * B_SZ + bglobal) * 2 * H_DIM + dircol + hcol] = hnew;
      }
    }

    // drain all stores to the coherence point, then post arrival
    asm volatile("s_waitcnt vmcnt(0)" ::: "memory");
    __syncthreads();
    if (tid == 0)
      __hip_atomic_store(&fl[cg], (unsigned)(t + 2), __ATOMIC_RELAXED, __HIP_MEMORY_SCOPE_AGENT);

    // ---- off-chain tail: x-part for step t+1 ----
    if (t + 1 < T_LEN) {
      if (layer == 1) {
        // need y0[p_{t+1}]: layer-0 published it when its flags reached t+3
        if (tid < 32) {
          const unsigned tgt = (unsigned)(t + 3);
          while (__hip_atomic_load(&fl0[tid], __ATOMIC_RELAXED, __HIP_MEMORY_SCOPE_AGENT) < tgt)
            __builtin_amdgcn_s_sleep(1);
        }
        __syncthreads();
      }
      const int tnext = dir ? (T_LEN - 2 - t) : (t + 1);
      acc_main[0] = 0.f; acc_main[1] = 0.f; acc_main[2] = 0.f; acc_main[3] = 0.f;
      xpart(tnext, acc_main);
    }
  }

  // layer 1: flush the last delayed output (after everyone finished step T-1)
  if (layer == 1) {
    if (tid < 32) {
      const unsigned tgt = (unsigned)(T_LEN + 1);
      while (__hip_atomic_load(&fl[tid], __ATOMIC_RELAXED, __HIP_MEMORY_SCOPE_AGENT) < tgt)
        __builtin_amdgcn_s_sleep(1);
    }
    __syncthreads();
    const int tlast = dir ? 0 : (T_LEN - 1);
    dout[(size_t)bglobal * T_LEN * 2 * H_DIM + (size_t)tlast * 2 * H_DIM + dircol + hcol] = yprev;
  }
}

extern "C" void kernel_launch(void* const* d_in, const int* in_sizes, int n_in,
                              void* d_out, int out_size, void* d_ws, size_t ws_size,
                              hipStream_t stream) {
  (void)in_sizes; (void)n_in; (void)out_size; (void)ws_size;
  const float* x    = (const float*)d_in[0];
  const float* enc  = (const float*)d_in[1];
  const float* WihF = (const float*)d_in[2];
  const float* WhhF = (const float*)d_in[3];
  const float* bihF = (const float*)d_in[4];
  const float* bhhF = (const float*)d_in[5];
  const float* WihB = (const float*)d_in[6];
  const float* WhhB = (const float*)d_in[7];
  const float* bihB = (const float*)d_in[8];
  const float* bhhB = (const float*)d_in[9];
  float* out = (float*)d_out;

  unsigned* flags = (unsigned*)d_ws;                      // 16 groups x 256B
  unsigned short* hbuf = (unsigned short*)((char*)d_ws + 4096);  // 512KB
  hipMemsetAsync(d_ws, 0, 4096, stream);                  // zero flags each replay

  dim3 grid(2 * GROUP * 8), block(256);
  gru_fused<<<grid, block, 0, stream>>>(x, enc, WihF, WhhF, bihF, bhhF,
                                        WihB, WhhB, bihB, bhhB, out, flags, hbuf);
}

// Round 5
// 9009.539 us; speedup vs baseline: 1.1999x; 1.1999x over previous
//
#include <hip/hip_runtime.h>
#include <hip/hip_bf16.h>
#include <cstdint>
#include <cstddef>

// Problem constants
#define T_LEN 1024
#define B_SZ  64
#define H_DIM 512
#define D_IN  512

// Decomposition: 2 dirs x 4 batch-groups (16 rows) x 32 col-groups (16 cols).
// Each block runs BOTH layers (layer-1 trails layer-0 by 2 supersteps).
#define NBG   4
#define GROUP 32
#define BS    16
#define CW    16

typedef __attribute__((ext_vector_type(8))) short short8;
typedef __attribute__((ext_vector_type(4))) float f32x4;
typedef unsigned long long ull;

// LDS layout (bytes): Whh(L0) 48K | Whh(L1) 48K | H 16K | X 16K | D 5K = 133K -> 1 block/CU
#define OFF_WHH0 0
#define OFF_WHH1 49152
#define OFF_H    98304
#define OFF_X    114688
#define OFF_D    131072
#define SMEM_BYTES 136192

__device__ __forceinline__ int swz(int row, int byteoff) {
  // XOR-swizzle 16B granules within a row (breaks stride-1024 bank conflicts).
  return byteoff ^ ((row & 7) << 4);
}

__device__ __forceinline__ unsigned short f2bf(float f) {
  unsigned u = __float_as_uint(f);
  return (unsigned short)((u + 0x7FFFu + ((u >> 16) & 1u)) >> 16);   // RNE
}

__device__ __forceinline__ short8 pack8(float4 a, float4 b) {
  short8 v;
  v[0] = (short)f2bf(a.x); v[1] = (short)f2bf(a.y);
  v[2] = (short)f2bf(a.z); v[3] = (short)f2bf(a.w);
  v[4] = (short)f2bf(b.x); v[5] = (short)f2bf(b.y);
  v[6] = (short)f2bf(b.z); v[7] = (short)f2bf(b.w);
  return v;
}

__device__ __forceinline__ unsigned cvtpk(float lo, float hi) {
  unsigned r;
  asm("v_cvt_pk_bf16_f32 %0, %1, %2" : "=v"(r) : "v"(lo), "v"(hi));   // RNE
  return r;
}
__device__ __forceinline__ short8 cvtpk8(float4 a, float4 b) {
  union { unsigned u[4]; short8 s; } cv;
  cv.u[0] = cvtpk(a.x, a.y); cv.u[1] = cvtpk(a.z, a.w);
  cv.u[2] = cvtpk(b.x, b.y); cv.u[3] = cvtpk(b.z, b.w);
  return cv.s;
}

__device__ __forceinline__ float sigm(float x) { return 1.0f / (1.0f + __expf(-x)); }
__device__ __forceinline__ float fast_tanh(float x) { return 1.0f - 2.0f / (__expf(2.0f * x) + 1.0f); }

__device__ __forceinline__ size_t hidx(int layer, int par, int dir, int bg, int row, int col) {
  const int g = ((layer * 2 + par) * 2 + dir) * NBG + bg;
  return ((size_t)g * BS + row) * H_DIM + col;              // hbuf: 512KB bf16
}
__device__ __forceinline__ size_t ridx(int par, int dir, int bg, int row, int col) {
  const int g = (par * 2 + dir) * NBG + bg;
  return ((size_t)g * BS + row) * H_DIM + col;              // y0ring: 512KB bf16
}

__global__ __launch_bounds__(256, 1)
void gru_fused(const float* __restrict__ x,
               const float* __restrict__ enc,
               const float* __restrict__ WihF, const float* __restrict__ WhhF,
               const float* __restrict__ bihF, const float* __restrict__ bhhF,
               const float* __restrict__ WihB, const float* __restrict__ WhhB,
               const float* __restrict__ bihB, const float* __restrict__ bhhB,
               float* __restrict__ dout,
               unsigned* __restrict__ flags,
               unsigned short* __restrict__ hbuf,
               unsigned short* __restrict__ y0ring)
{
  __shared__ alignas(16) char smem[SMEM_BYTES];

  const int bid  = blockIdx.x;
  const int grp  = bid & 7;          // dir*4+bg (same mod-8 => same XCD under round-robin; perf only)
  const int dir  = grp >> 2;
  const int bg   = grp & 3;
  const int cg   = bid >> 3;         // col-group 0..31
  const int tid  = threadIdx.x;
  const int wv   = tid >> 6;
  const int tb   = tid >> 4;         // staging row / batch-local row
  const int tc   = tid & 15;         // staging segment / col-local
  const int lrow = tc;               // MFMA fragment row (= lane&15)
  const int q    = tb & 3;           // MFMA k-quarter (= lane>>4)
  const int hc0  = cg * CW;
  const int hcol = hc0 + tc;
  const int bglobal = bg * BS + tb;
  const int dircol  = dir * H_DIM;

  const float* Wih0 = (dir ? WihB : WihF);
  const float* Whh0 = (dir ? WhhB : WhhF);
  const float* bih0 = (dir ? bihB : bihF);
  const float* bhh0 = (dir ? bhhB : bhhF);
  const float* Wih1 = Wih0 + (size_t)3 * H_DIM * D_IN;
  const float* Whh1 = Whh0 + (size_t)3 * H_DIM * H_DIM;
  const float* bih1 = bih0 + 3 * H_DIM;
  const float* bhh1 = bhh0 + 3 * H_DIM;

  unsigned* fl0 = flags + grp * 64;        // layer-0 producer flags (32)
  unsigned* fl1 = flags + (8 + grp) * 64;  // layer-1 producer flags (32)

  // ---- Stage Whh for BOTH layers into LDS (once) ----
  #pragma unroll
  for (int g = 0; g < 3; ++g) {
    {
      const float* s = Whh0 + (size_t)(g * H_DIM + hc0 + tb) * H_DIM + tc * 32;
      char* r = smem + OFF_WHH0 + g * 16384 + tb * 1024;
      #pragma unroll
      for (int u = 0; u < 4; ++u) {
        float4 a = ((const float4*)s)[u * 2];
        float4 b = ((const float4*)s)[u * 2 + 1];
        *(short8*)(r + swz(tb, tc * 64 + u * 16)) = pack8(a, b);
      }
    }
    {
      const float* s = Whh1 + (size_t)(g * H_DIM + hc0 + tb) * H_DIM + tc * 32;
      char* r = smem + OFF_WHH1 + g * 16384 + tb * 1024;
      #pragma unroll
      for (int u = 0; u < 4; ++u) {
        float4 a = ((const float4*)s)[u * 2];
        float4 b = ((const float4*)s)[u * 2 + 1];
        *(short8*)(r + swz(tb, tc * 64 + u * 16)) = pack8(a, b);
      }
    }
  }

  // ---- Persistent Wih B-fragments in registers, both layers ----
  short8 wf0[16], wf1[16];
  if (wv < 3) {
    const float* p0 = Wih0 + (size_t)(wv * H_DIM + hc0 + lrow) * D_IN;
    const float* p1 = Wih1 + (size_t)(wv * H_DIM + hc0 + lrow) * D_IN;
    #pragma unroll
    for (int kc = 0; kc < 16; ++kc) {
      const int k0 = kc * 32 + q * 8;
      wf0[kc] = cvtpk8(*(const float4*)(p0 + k0), *(const float4*)(p0 + k0 + 4));
      wf1[kc] = cvtpk8(*(const float4*)(p1 + k0), *(const float4*)(p1 + k0 + 4));
    }
  }

  // ---- Biases and initial hidden states ----
  const float b_r0  = bih0[hcol] + bhh0[hcol];
  const float b_z0  = bih0[H_DIM + hcol] + bhh0[H_DIM + hcol];
  const float b_xn0 = bih0[2 * H_DIM + hcol];
  const float b_hn0 = bhh0[2 * H_DIM + hcol];
  const float b_r1  = bih1[hcol] + bhh1[hcol];
  const float b_z1  = bih1[H_DIM + hcol] + bhh1[H_DIM + hcol];
  const float b_xn1 = bih1[2 * H_DIM + hcol];
  const float b_hn1 = bhh1[2 * H_DIM + hcol];
  float h0reg = enc[(size_t)bglobal * 2 * H_DIM + dircol + hcol];
  float h1reg = enc[(size_t)B_SZ * 2 * H_DIM + (size_t)bglobal * 2 * H_DIM + dircol + hcol];

  // ---- helpers ----
  auto pub16 = [&](float val, unsigned short* dst) {
    unsigned v = f2bf(val);
    unsigned v1 = __shfl_down(v, 1);
    unsigned v2 = __shfl_down(v, 2);
    unsigned v3 = __shfl_down(v, 3);
    if ((tc & 3) == 0) {
      ull pk = (ull)v | ((ull)v1 << 16) | ((ull)v2 << 32) | ((ull)v3 << 48);
      __hip_atomic_store((ull*)dst, pk, __ATOMIC_RELAXED, __HIP_MEMORY_SCOPE_AGENT);
    }
  };
  auto poll32 = [&](unsigned* fl, unsigned tgt) {
    if (tid < 32) {
      while (__hip_atomic_load(&fl[tid], __ATOMIC_RELAXED, __HIP_MEMORY_SCOPE_AGENT) < tgt)
        __builtin_amdgcn_s_sleep(1);
    }
    __syncthreads();
  };
  auto stage_x = [&](int pos) {   // fp32 global row -> bf16 LDS X tile
    const float* xrow = x + ((size_t)bglobal * T_LEN + pos) * D_IN;
    const float4* s4 = (const float4*)(xrow + tc * 32);
    char* lx = smem + OFF_X + tb * 1024;
    #pragma unroll
    for (int u = 0; u < 4; ++u) {
      float4 a = s4[u * 2];
      float4 b = s4[u * 2 + 1];
      *(short8*)(lx + swz(tb, tc * 64 + u * 16)) = pack8(a, b);
    }
  };
  auto gather_bf16 = [&](const unsigned short* src, int ldsOff) {  // agent 8B loads -> LDS
    const ull* sb = (const ull*)(src + tc * 32);
    ull hv[8];
    #pragma unroll
    for (int u = 0; u < 8; ++u)
      hv[u] = __hip_atomic_load(sb + u, __ATOMIC_RELAXED, __HIP_MEMORY_SCOPE_AGENT);
    char* lh = smem + ldsOff + tb * 1024;
    #pragma unroll
    for (int u = 0; u < 4; ++u) {
      ull tmp[2] = {hv[2 * u], hv[2 * u + 1]};
      *(short8*)(lh + swz(tb, tc * 64 + u * 16)) = *(const short8*)tmp;
    }
  };
  auto xpart = [&](const short8* wf, f32x4& am) {   // X (LDS) x Wih (regs)
    if (wv < 3) {
      char* xr = smem + OFF_X + lrow * 1024;
      #pragma unroll
      for (int kc = 0; kc < 16; ++kc) {
        short8 a = *(const short8*)(xr + swz(lrow, kc * 64 + q * 16));
        am = __builtin_amdgcn_mfma_f32_16x16x32_bf16(a, wf[kc], am, 0, 0, 0);
      }
    }
  };
  auto hpart = [&](int whhOff, f32x4& am, f32x4& ah) {   // H (LDS) x Whh (LDS)
    char* hr = smem + OFF_H + lrow * 1024;
    if (wv < 2) {
      char* wrow = smem + whhOff + wv * 16384 + lrow * 1024;
      #pragma unroll
      for (int kc = 0; kc < 16; ++kc) {
        short8 a = *(const short8*)(hr + swz(lrow, kc * 64 + q * 16));
        short8 b = *(const short8*)(wrow + swz(lrow, kc * 64 + q * 16));
        am = __builtin_amdgcn_mfma_f32_16x16x32_bf16(a, b, am, 0, 0, 0);
      }
    } else {
      char* wrow = smem + whhOff + 2 * 16384 + lrow * 1024;
      const int k0 = (wv == 2) ? 0 : 8;
      #pragma unroll
      for (int kc = 0; kc < 8; ++kc) {
        short8 a = *(const short8*)(hr + swz(lrow, (k0 + kc) * 64 + q * 16));
        short8 b = *(const short8*)(wrow + swz(lrow, (k0 + kc) * 64 + q * 16));
        ah = __builtin_amdgcn_mfma_f32_16x16x32_bf16(a, b, ah, 0, 0, 0);
      }
    }
  };
  auto dwrite = [&](const f32x4& am, const f32x4& ah) {
    if (wv < 3) {
      float* dt = (float*)(smem + OFF_D + wv * 1024);
      #pragma unroll
      for (int r = 0; r < 4; ++r)
        dt[(q * 4 + r) * 16 + ((lrow + 4 * q) & 15)] = am[r];
    }
    if (wv >= 2) {
      float* dt = (float*)(smem + OFF_D + (wv + 1) * 1024);
      #pragma unroll
      for (int r = 0; r < 4; ++r)
        dt[(q * 4 + r) * 16 + ((lrow + 4 * q) & 15)] = ah[r];
    }
  };
  auto gates = [&](float br, float bz, float bxn, float bhn, float hprev) -> float {
    const float* Dr  = (const float*)(smem + OFF_D);
    const float* Dz  = (const float*)(smem + OFF_D + 1024);
    const float* Dxn = (const float*)(smem + OFF_D + 2048);
    const float* Dha = (const float*)(smem + OFF_D + 3072);
    const float* Dhb = (const float*)(smem + OFF_D + 4096);
    const int e = tb * 16 + ((tc + 4 * (tb >> 2)) & 15);
    const float r = sigm(Dr[e] + br);
    const float z = sigm(Dz[e] + bz);
    const float n = fast_tanh(Dxn[e] + bxn + r * (Dha[e] + Dhb[e] + bhn));
    return (1.0f - z) * n + z * hprev;
  };

  // ---- publish h0/h1 (parity 0), post flags=1 ----
  pub16(h0reg, &hbuf[hidx(0, 0, dir, bg, tb, hcol)]);
  pub16(h1reg, &hbuf[hidx(1, 0, dir, bg, tb, hcol)]);
  asm volatile("s_waitcnt vmcnt(0)" ::: "memory");
  __syncthreads();   // also covers Whh LDS staging
  if (tid == 0) {
    __hip_atomic_store(&fl0[cg], 1u, __ATOMIC_RELAXED, __HIP_MEMORY_SCOPE_AGENT);
    __hip_atomic_store(&fl1[cg], 1u, __ATOMIC_RELAXED, __HIP_MEMORY_SCOPE_AGENT);
  }

  // ---- prologue: layer-0 x-part for t=0 ----
  f32x4 acc0 = {0.f, 0.f, 0.f, 0.f};
  f32x4 acc1 = {0.f, 0.f, 0.f, 0.f};
  stage_x(dir ? (T_LEN - 1) : 0);
  __syncthreads();
  xpart(wf0, acc0);

  for (int t = 0; t < T_LEN + 2; ++t) {
    // ======== Phase A: layer-0 step t (on-chain) ========
    if (t < T_LEN) {
      poll32(fl0, (unsigned)(t + 1));
      gather_bf16(&hbuf[hidx(0, t & 1, dir, bg, tb, 0)], OFF_H);
      __syncthreads();
      f32x4 ah = {0.f, 0.f, 0.f, 0.f};
      hpart(OFF_WHH0, acc0, ah);
      dwrite(acc0, ah);
      __syncthreads();
      const float h0new = gates(b_r0, b_z0, b_xn0, b_hn0, h0reg);
      h0reg = h0new;
      pub16(h0new, &hbuf[hidx(0, (t + 1) & 1, dir, bg, tb, hcol)]);
      pub16(h0new, &y0ring[ridx(t & 3, dir, bg, tb, hcol)]);
      if (t == T_LEN - 1)
        dout[(size_t)B_SZ * T_LEN * 2 * H_DIM + (size_t)bglobal * 2 * H_DIM + dircol + hcol] = h0new;
      asm volatile("s_waitcnt vmcnt(0)" ::: "memory");
      __syncthreads();
      if (tid == 0)
        __hip_atomic_store(&fl0[cg], (unsigned)(t + 2), __ATOMIC_RELAXED, __HIP_MEMORY_SCOPE_AGENT);
    } else if (t == T_LEN) {
      // ensure all peers published y0(T-1) before C2 below reads it
      poll32(fl0, (unsigned)(T_LEN + 1));
    }

    // ======== Phase B: layer-0 x-part for t+1 (off-chain) ========
    if (t + 1 < T_LEN) {
      stage_x(dir ? (T_LEN - 2 - t) : (t + 1));
      __syncthreads();
      acc0[0] = 0.f; acc0[1] = 0.f; acc0[2] = 0.f; acc0[3] = 0.f;
      xpart(wf0, acc0);
    }

    // ======== Phase C: layer-1 step u = t-2 ========
    const int u = t - 2;
    if (u >= 0) {
      poll32(fl1, (unsigned)(u + 1));
      gather_bf16(&hbuf[hidx(1, u & 1, dir, bg, tb, 0)], OFF_H);
      __syncthreads();
      f32x4 ah = {0.f, 0.f, 0.f, 0.f};
      hpart(OFF_WHH1, acc1, ah);
      dwrite(acc1, ah);
      __syncthreads();
      const float h1new = gates(b_r1, b_z1, b_xn1, b_hn1, h1reg);
      h1reg = h1new;
      pub16(h1new, &hbuf[hidx(1, (u + 1) & 1, dir, bg, tb, hcol)]);
      const int pu = dir ? (T_LEN - 1 - u) : u;
      dout[(size_t)bglobal * T_LEN * 2 * H_DIM + (size_t)pu * 2 * H_DIM + dircol + hcol] = h1new;
      if (u == T_LEN - 1)
        dout[(size_t)B_SZ * T_LEN * 2 * H_DIM +
             (size_t)(B_SZ + bglobal) * 2 * H_DIM + dircol + hcol] = h1new;
      asm volatile("s_waitcnt vmcnt(0)" ::: "memory");
      __syncthreads();
      if (tid == 0)
        __hip_atomic_store(&fl1[cg], (unsigned)(u + 2), __ATOMIC_RELAXED, __HIP_MEMORY_SCOPE_AGENT);
    }

    // ======== Phase C2: layer-1 x-part for step t-1 from y0 ring ========
    if (t >= 1 && t <= T_LEN) {
      __syncthreads();   // order earlier X readers before overwrite
      gather_bf16(y0ring + ridx((t - 1) & 3, dir, bg, tb, 0), OFF_X);
      __syncthreads();
      acc1[0] = 0.f; acc1[1] = 0.f; acc1[2] = 0.f; acc1[3] = 0.f;
      xpart(wf1, acc1);
    }
  }
}

extern "C" void kernel_launch(void* const* d_in, const int* in_sizes, int n_in,
                              void* d_out, int out_size, void* d_ws, size_t ws_size,
                              hipStream_t stream) {
  (void)in_sizes; (void)n_in; (void)out_size; (void)ws_size;
  const float* x    = (const float*)d_in[0];
  const float* enc  = (const float*)d_in[1];
  const float* WihF = (const float*)d_in[2];
  const float* WhhF = (const float*)d_in[3];
  const float* bihF = (const float*)d_in[4];
  const float* bhhF = (const float*)d_in[5];
  const float* WihB = (const float*)d_in[6];
  const float* WhhB = (const float*)d_in[7];
  const float* bihB = (const float*)d_in[8];
  const float* bhhB = (const float*)d_in[9];
  float* out = (float*)d_out;

  unsigned* flags = (unsigned*)d_ws;                                   // 4KB
  unsigned short* hbuf   = (unsigned short*)((char*)d_ws + 4096);      // 512KB
  unsigned short* y0ring = (unsigned short*)((char*)d_ws + 4096 + 524288); // 512KB
  hipMemsetAsync(d_ws, 0, 4096, stream);   // zero flags each replay

  dim3 grid(GROUP * 8), block(256);
  gru_fused<<<grid, block, 0, stream>>>(x, enc, WihF, WhhF, bihF, bhhF,
                                        WihB, WhhB, bihB, bhhB, out, flags, hbuf, y0ring);
}

// Round 6
// 8876.263 us; speedup vs baseline: 1.2180x; 1.0150x over previous
//
#include <hip/hip_runtime.h>
#include <hip/hip_bf16.h>
#include <cstdint>
#include <cstddef>

// Problem constants
#define T_LEN 1024
#define B_SZ  64
#define H_DIM 512
#define D_IN  512

// Decomposition: 2 dirs x 4 batch-groups (16 rows) x 32 col-groups (16 cols).
// Each block runs BOTH layers (layer-1 trails layer-0 by 2 supersteps).
#define NBG   4
#define GROUP 32
#define BS    16
#define CW    16

typedef __attribute__((ext_vector_type(8))) short short8;
typedef __attribute__((ext_vector_type(4))) float f32x4;
typedef __attribute__((ext_vector_type(4))) int   i32x4;
typedef unsigned long long ull;

// LDS layout (bytes): Whh(L0) 48K | Whh(L1) 48K | H 16K | X 16K | D 5K -> 1 block/CU
#define OFF_WHH0 0
#define OFF_WHH1 49152
#define OFF_H    98304
#define OFF_X    114688
#define OFF_D    131072
#define SMEM_BYTES 136192

// Tagged-unit exchange geometry.
// Unit = 16B: u16[0..6] = 7 bf16 values, u16[7] = step tag (>=1; memset gives 0).
// Per (state,row): 32 col-groups x 3 units = 1536B. Per state: 16 rows.
#define ROW_BYTES   1536
#define STATE_BYTES (16 * ROW_BYTES)   // 24576
#define HT_BYTES    (32 * STATE_BYTES) // 786432: states = (layer*2+par)*8+grp
#define YT_BYTES    (32 * STATE_BYTES) // 786432: states = slot*8+grp

__device__ __forceinline__ int swz(int row, int byteoff) {
  return byteoff ^ ((row & 7) << 4);   // break stride-1024 LDS bank conflicts
}

__device__ __forceinline__ unsigned short f2bf(float f) {
  unsigned u = __float_as_uint(f);
  return (unsigned short)((u + 0x7FFFu + ((u >> 16) & 1u)) >> 16);   // RNE
}

__device__ __forceinline__ short8 pack8(float4 a, float4 b) {
  short8 v;
  v[0] = (short)f2bf(a.x); v[1] = (short)f2bf(a.y);
  v[2] = (short)f2bf(a.z); v[3] = (short)f2bf(a.w);
  v[4] = (short)f2bf(b.x); v[5] = (short)f2bf(b.y);
  v[6] = (short)f2bf(b.z); v[7] = (short)f2bf(b.w);
  return v;
}

__device__ __forceinline__ unsigned cvtpk(float lo, float hi) {
  unsigned r;
  asm("v_cvt_pk_bf16_f32 %0, %1, %2" : "=v"(r) : "v"(lo), "v"(hi));
  return r;
}
__device__ __forceinline__ short8 cvtpk8(float4 a, float4 b) {
  union { unsigned u[4]; short8 s; } cv;
  cv.u[0] = cvtpk(a.x, a.y); cv.u[1] = cvtpk(a.z, a.w);
  cv.u[2] = cvtpk(b.x, b.y); cv.u[3] = cvtpk(b.z, b.w);
  return cv.s;
}

__device__ __forceinline__ float sigm(float x) { return 1.0f / (1.0f + __expf(-x)); }
__device__ __forceinline__ float fast_tanh(float x) { return 1.0f - 2.0f / (__expf(2.0f * x) + 1.0f); }

// agent-scope (sc1) 16B store: fire-and-forget tagged unit
__device__ __forceinline__ void st16(void* p, i32x4 d) {
  asm volatile("global_store_dwordx4 %0, %1, off sc1" :: "v"(p), "v"(d) : "memory");
}

// repack two producers' 7/7/2-packed triple into contiguous bf16x8 pairs
__device__ __forceinline__ void repack_triple(i32x4 Ua, i32x4 Ub, i32x4 Uc,
                                              short8& s0, short8& s1) {
  union { unsigned u[4]; short8 s; } A, B;
  A.u[0] = (unsigned)Ua[0];
  A.u[1] = (unsigned)Ua[1];
  A.u[2] = (unsigned)Ua[2];
  A.u[3] = ((unsigned)Ua[3] & 0xffffu) | ((unsigned)Ub[0] << 16);
  B.u[0] = ((unsigned)Ub[0] >> 16) | ((unsigned)Ub[1] << 16);
  B.u[1] = ((unsigned)Ub[1] >> 16) | ((unsigned)Ub[2] << 16);
  B.u[2] = ((unsigned)Ub[2] >> 16) | (((unsigned)Ub[3] & 0xffffu) << 16);
  B.u[3] = (unsigned)Uc[0];
  s0 = A.s; s1 = B.s;
}

__global__ __launch_bounds__(256, 1)
void gru_fused(const float* __restrict__ x,
               const float* __restrict__ enc,
               const float* __restrict__ WihF, const float* __restrict__ WhhF,
               const float* __restrict__ bihF, const float* __restrict__ bhhF,
               const float* __restrict__ WihB, const float* __restrict__ WhhB,
               const float* __restrict__ bihB, const float* __restrict__ bhhB,
               float* __restrict__ dout,
               char* __restrict__ hT,
               char* __restrict__ yT)
{
  __shared__ alignas(16) char smem[SMEM_BYTES];

  const int bid  = blockIdx.x;
  const int grp  = bid & 7;          // dir*4+bg (mod-8 => same XCD round-robin; perf only)
  const int dir  = grp >> 2;
  const int bg   = grp & 3;
  const int cg   = bid >> 3;         // col-group 0..31
  const int tid  = threadIdx.x;
  const int wv   = tid >> 6;
  const int tb   = tid >> 4;         // batch-local row / staging row
  const int tc   = tid & 15;         // col-local / staging segment
  const int lrow = tc;               // MFMA fragment row
  const int q    = tb & 3;           // MFMA k-quarter
  const int hc0  = cg * CW;
  const int hcol = hc0 + tc;
  const int bglobal = bg * BS + tb;
  const int dircol  = dir * H_DIM;

  const bool isPub = (tc == 0) | (tc == 7) | (tc == 14);
  const int  which = (tc == 0) ? 0 : ((tc == 7) ? 1 : 2);

  const float* Wih0 = (dir ? WihB : WihF);
  const float* Whh0 = (dir ? WhhB : WhhF);
  const float* bih0 = (dir ? bihB : bihF);
  const float* bhh0 = (dir ? bhhB : bhhF);
  const float* Wih1 = Wih0 + (size_t)3 * H_DIM * D_IN;
  const float* Whh1 = Whh0 + (size_t)3 * H_DIM * H_DIM;
  const float* bih1 = bih0 + 3 * H_DIM;
  const float* bhh1 = bhh0 + 3 * H_DIM;

  // ---- Stage Whh for BOTH layers into LDS (once) ----
  #pragma unroll
  for (int g = 0; g < 3; ++g) {
    {
      const float* s = Whh0 + (size_t)(g * H_DIM + hc0 + tb) * H_DIM + tc * 32;
      char* r = smem + OFF_WHH0 + g * 16384 + tb * 1024;
      #pragma unroll
      for (int u = 0; u < 4; ++u) {
        float4 a = ((const float4*)s)[u * 2];
        float4 b = ((const float4*)s)[u * 2 + 1];
        *(short8*)(r + swz(tb, tc * 64 + u * 16)) = pack8(a, b);
      }
    }
    {
      const float* s = Whh1 + (size_t)(g * H_DIM + hc0 + tb) * H_DIM + tc * 32;
      char* r = smem + OFF_WHH1 + g * 16384 + tb * 1024;
      #pragma unroll
      for (int u = 0; u < 4; ++u) {
        float4 a = ((const float4*)s)[u * 2];
        float4 b = ((const float4*)s)[u * 2 + 1];
        *(short8*)(r + swz(tb, tc * 64 + u * 16)) = pack8(a, b);
      }
    }
  }

  // ---- Persistent Wih B-fragments in registers, both layers ----
  short8 wf0[16], wf1[16];
  if (wv < 3) {
    const float* p0 = Wih0 + (size_t)(wv * H_DIM + hc0 + lrow) * D_IN;
    const float* p1 = Wih1 + (size_t)(wv * H_DIM + hc0 + lrow) * D_IN;
    #pragma unroll
    for (int kc = 0; kc < 16; ++kc) {
      const int k0 = kc * 32 + q * 8;
      wf0[kc] = cvtpk8(*(const float4*)(p0 + k0), *(const float4*)(p0 + k0 + 4));
      wf1[kc] = cvtpk8(*(const float4*)(p1 + k0), *(const float4*)(p1 + k0 + 4));
    }
  }

  // ---- Biases and initial hidden states ----
  const float b_r0  = bih0[hcol] + bhh0[hcol];
  const float b_z0  = bih0[H_DIM + hcol] + bhh0[H_DIM + hcol];
  const float b_xn0 = bih0[2 * H_DIM + hcol];
  const float b_hn0 = bhh0[2 * H_DIM + hcol];
  const float b_r1  = bih1[hcol] + bhh1[hcol];
  const float b_z1  = bih1[H_DIM + hcol] + bhh1[H_DIM + hcol];
  const float b_xn1 = bih1[2 * H_DIM + hcol];
  const float b_hn1 = bhh1[2 * H_DIM + hcol];
  float h0reg = enc[(size_t)bglobal * 2 * H_DIM + dircol + hcol];
  float h1reg = enc[(size_t)B_SZ * 2 * H_DIM + (size_t)bglobal * 2 * H_DIM + dircol + hcol];

  // ---- exchange-buffer base helpers ----
  auto stateH = [&](int layer, int par) -> char* {
    return hT + (size_t)(((layer * 2 + par) * 8) + grp) * STATE_BYTES;
  };
  auto stateY = [&](int slot) -> char* {
    return yT + (size_t)(slot * 8 + grp) * STATE_BYTES;
  };

  // publish this thread's value (with its row-neighbors) as tagged units
  auto pubH = [&](float val, char* sb, unsigned tag) {
    unsigned v  = f2bf(val);
    unsigned v1 = __shfl_down(v, 1), v2 = __shfl_down(v, 2), v3 = __shfl_down(v, 3);
    unsigned v4 = __shfl_down(v, 4), v5 = __shfl_down(v, 5), v6 = __shfl_down(v, 6);
    if (isPub) {
      i32x4 U;
      U[0] = (int)(v  | (v1 << 16));
      U[1] = (int)(v2 | (v3 << 16));
      U[2] = (int)(v4 | (v5 << 16));
      U[3] = (int)((v6 & 0xffffu) | (tag << 16));
      st16(sb + (size_t)tb * ROW_BYTES + cg * 48 + which * 16, U);
    }
  };
  auto pubDual = [&](float val, char* sbH, unsigned tagH, char* sbY, unsigned tagY) {
    unsigned v  = f2bf(val);
    unsigned v1 = __shfl_down(v, 1), v2 = __shfl_down(v, 2), v3 = __shfl_down(v, 3);
    unsigned v4 = __shfl_down(v, 4), v5 = __shfl_down(v, 5), v6 = __shfl_down(v, 6);
    if (isPub) {
      i32x4 U;
      U[0] = (int)(v  | (v1 << 16));
      U[1] = (int)(v2 | (v3 << 16));
      U[2] = (int)(v4 | (v5 << 16));
      i32x4 Uh = U, Uy = U;
      Uh[3] = (int)((v6 & 0xffffu) | (tagH << 16));
      Uy[3] = (int)((v6 & 0xffffu) | (tagY << 16));
      const size_t off = (size_t)tb * ROW_BYTES + cg * 48 + which * 16;
      st16(sbH + off, Uh);
      st16(sbY + off, Uy);
    }
  };

  // poll+gather: thread (tb,tc) owns row tb, cols [32tc,32tc+32) = producers 2tc,2tc+1
  auto gatherTagged = [&](const char* sb, unsigned tag, int ldsOff) {
    const char* a0 = sb + (size_t)tb * ROW_BYTES + (2 * tc) * 48;
    const char* a1 = a0 + 48;
    i32x4 U0, U1, U2, U3, U4, U5;
    for (;;) {
      asm volatile(
        "global_load_dwordx4 %0, %6, off sc1\n\t"
        "global_load_dwordx4 %1, %6, off offset:16 sc1\n\t"
        "global_load_dwordx4 %2, %6, off offset:32 sc1\n\t"
        "global_load_dwordx4 %3, %7, off sc1\n\t"
        "global_load_dwordx4 %4, %7, off offset:16 sc1\n\t"
        "global_load_dwordx4 %5, %7, off offset:32 sc1\n\t"
        "s_waitcnt vmcnt(0)"
        : "=&v"(U0), "=&v"(U1), "=&v"(U2), "=&v"(U3), "=&v"(U4), "=&v"(U5)
        : "v"(a0), "v"(a1)
        : "memory");
      const bool ok = (((unsigned)U0[3] >> 16) == tag) & (((unsigned)U1[3] >> 16) == tag) &
                      (((unsigned)U2[3] >> 16) == tag) & (((unsigned)U3[3] >> 16) == tag) &
                      (((unsigned)U4[3] >> 16) == tag) & (((unsigned)U5[3] >> 16) == tag);
      if (ok) break;
      __builtin_amdgcn_s_sleep(2);
    }
    short8 s0, s1, s2, s3;
    repack_triple(U0, U1, U2, s0, s1);
    repack_triple(U3, U4, U5, s2, s3);
    char* lh = smem + ldsOff + tb * 1024;
    *(short8*)(lh + swz(tb, tc * 64 +  0)) = s0;
    *(short8*)(lh + swz(tb, tc * 64 + 16)) = s1;
    *(short8*)(lh + swz(tb, tc * 64 + 32)) = s2;
    *(short8*)(lh + swz(tb, tc * 64 + 48)) = s3;
  };

  auto stage_x = [&](int pos) {   // fp32 global row -> bf16 LDS X tile
    const float* xrow = x + ((size_t)bglobal * T_LEN + pos) * D_IN;
    const float4* s4 = (const float4*)(xrow + tc * 32);
    char* lx = smem + OFF_X + tb * 1024;
    #pragma unroll
    for (int u = 0; u < 4; ++u) {
      float4 a = s4[u * 2];
      float4 b = s4[u * 2 + 1];
      *(short8*)(lx + swz(tb, tc * 64 + u * 16)) = pack8(a, b);
    }
  };
  auto xpart = [&](const short8* wf, f32x4& am) {   // X (LDS) x Wih (regs)
    if (wv < 3) {
      char* xr = smem + OFF_X + lrow * 1024;
      #pragma unroll
      for (int kc = 0; kc < 16; ++kc) {
        short8 a = *(const short8*)(xr + swz(lrow, kc * 64 + q * 16));
        am = __builtin_amdgcn_mfma_f32_16x16x32_bf16(a, wf[kc], am, 0, 0, 0);
      }
    }
  };
  auto hpart = [&](int whhOff, f32x4& am, f32x4& ah) {   // H (LDS) x Whh (LDS)
    char* hr = smem + OFF_H + lrow * 1024;
    if (wv < 2) {
      char* wrow = smem + whhOff + wv * 16384 + lrow * 1024;
      #pragma unroll
      for (int kc = 0; kc < 16; ++kc) {
        short8 a = *(const short8*)(hr + swz(lrow, kc * 64 + q * 16));
        short8 b = *(const short8*)(wrow + swz(lrow, kc * 64 + q * 16));
        am = __builtin_amdgcn_mfma_f32_16x16x32_bf16(a, b, am, 0, 0, 0);
      }
    } else {
      char* wrow = smem + whhOff + 2 * 16384 + lrow * 1024;
      const int k0 = (wv == 2) ? 0 : 8;
      #pragma unroll
      for (int kc = 0; kc < 8; ++kc) {
        short8 a = *(const short8*)(hr + swz(lrow, (k0 + kc) * 64 + q * 16));
        short8 b = *(const short8*)(wrow + swz(lrow, (k0 + kc) * 64 + q * 16));
        ah = __builtin_amdgcn_mfma_f32_16x16x32_bf16(a, b, ah, 0, 0, 0);
      }
    }
  };
  auto dwrite = [&](const f32x4& am, const f32x4& ah) {
    if (wv < 3) {
      float* dt = (float*)(smem + OFF_D + wv * 1024);
      #pragma unroll
      for (int r = 0; r < 4; ++r)
        dt[(q * 4 + r) * 16 + ((lrow + 4 * q) & 15)] = am[r];
    }
    if (wv >= 2) {
      float* dt = (float*)(smem + OFF_D + (wv + 1) * 1024);
      #pragma unroll
      for (int r = 0; r < 4; ++r)
        dt[(q * 4 + r) * 16 + ((lrow + 4 * q) & 15)] = ah[r];
    }
  };
  auto gates = [&](float br, float bz, float bxn, float bhn, float hprev) -> float {
    const float* Dr  = (const float*)(smem + OFF_D);
    const float* Dz  = (const float*)(smem + OFF_D + 1024);
    const float* Dxn = (const float*)(smem + OFF_D + 2048);
    const float* Dha = (const float*)(smem + OFF_D + 3072);
    const float* Dhb = (const float*)(smem + OFF_D + 4096);
    const int e = tb * 16 + ((tc + 4 * (tb >> 2)) & 15);
    const float r = sigm(Dr[e] + br);
    const float z = sigm(Dz[e] + bz);
    const float n = fast_tanh(Dxn[e] + bxn + r * (Dha[e] + Dhb[e] + bhn));
    return (1.0f - z) * n + z * hprev;
  };

  // ---- init: publish s_0 for both layers (tag 1, parity 0); fire-and-forget ----
  pubH(h0reg, stateH(0, 0), 1u);
  pubH(h1reg, stateH(1, 0), 1u);

  // ---- prologue: layer-0 x-part for t=0 ----
  f32x4 acc0 = {0.f, 0.f, 0.f, 0.f};
  f32x4 acc1 = {0.f, 0.f, 0.f, 0.f};
  stage_x(dir ? (T_LEN - 1) : 0);
  __syncthreads();
  xpart(wf0, acc0);

  for (int t = 0; t < T_LEN + 2; ++t) {
    // ======== Phase A: layer-0 step t ========
    if (t < T_LEN) {
      const int torig = dir ? (T_LEN - 1 - t) : t;
      gatherTagged(stateH(0, t & 1), (unsigned)(t + 1), OFF_H);
      __syncthreads();
      f32x4 ah = {0.f, 0.f, 0.f, 0.f};
      hpart(OFF_WHH0, acc0, ah);
      dwrite(acc0, ah);
      __syncthreads();
      const float h0new = gates(b_r0, b_z0, b_xn0, b_hn0, h0reg);
      h0reg = h0new;
      // publish h_{t+1} (tag t+2) and y0(t) (tag t+1) — no drain, no flags
      pubDual(h0new, stateH(0, (t + 1) & 1), (unsigned)(t + 2),
              stateY(t & 3), (unsigned)(t + 1));
      (void)torig;
      if (t == T_LEN - 1)
        dout[(size_t)B_SZ * T_LEN * 2 * H_DIM + (size_t)bglobal * 2 * H_DIM + dircol + hcol] = h0new;
    }

    // ======== Phase B: layer-0 x-part for t+1 (off-chain) ========
    if (t + 1 < T_LEN) {
      __syncthreads();   // order phase-A X readers (none) / prior C2 readers before overwrite
      stage_x(dir ? (T_LEN - 2 - t) : (t + 1));
      __syncthreads();
      acc0[0] = 0.f; acc0[1] = 0.f; acc0[2] = 0.f; acc0[3] = 0.f;
      xpart(wf0, acc0);
    }

    // ======== Phase C: layer-1 step u = t-2 ========
    const int u = t - 2;
    if (u >= 0) {
      gatherTagged(stateH(1, u & 1), (unsigned)(u + 1), OFF_H);
      __syncthreads();
      f32x4 ah = {0.f, 0.f, 0.f, 0.f};
      hpart(OFF_WHH1, acc1, ah);
      dwrite(acc1, ah);
      __syncthreads();
      const float h1new = gates(b_r1, b_z1, b_xn1, b_hn1, h1reg);
      h1reg = h1new;
      pubH(h1new, stateH(1, (u + 1) & 1), (unsigned)(u + 2));
      const int pu = dir ? (T_LEN - 1 - u) : u;
      dout[(size_t)bglobal * T_LEN * 2 * H_DIM + (size_t)pu * 2 * H_DIM + dircol + hcol] = h1new;
      if (u == T_LEN - 1)
        dout[(size_t)B_SZ * T_LEN * 2 * H_DIM +
             (size_t)(B_SZ + bglobal) * 2 * H_DIM + dircol + hcol] = h1new;
    }

    // ======== Phase C2: layer-1 x-part for step t-1 from tagged y0 ring ========
    if (t >= 1 && t <= T_LEN) {
      __syncthreads();   // order phase-B X readers before overwrite
      gatherTagged(stateY((t - 1) & 3), (unsigned)t, OFF_X);
      __syncthreads();
      acc1[0] = 0.f; acc1[1] = 0.f; acc1[2] = 0.f; acc1[3] = 0.f;
      xpart(wf1, acc1);
    }
  }
}

extern "C" void kernel_launch(void* const* d_in, const int* in_sizes, int n_in,
                              void* d_out, int out_size, void* d_ws, size_t ws_size,
                              hipStream_t stream) {
  (void)in_sizes; (void)n_in; (void)out_size; (void)ws_size;
  const float* x    = (const float*)d_in[0];
  const float* enc  = (const float*)d_in[1];
  const float* WihF = (const float*)d_in[2];
  const float* WhhF = (const float*)d_in[3];
  const float* bihF = (const float*)d_in[4];
  const float* bhhF = (const float*)d_in[5];
  const float* WihB = (const float*)d_in[6];
  const float* WhhB = (const float*)d_in[7];
  const float* bihB = (const float*)d_in[8];
  const float* bhhB = (const float*)d_in[9];
  float* out = (float*)d_out;

  char* hT = (char*)d_ws;                 // 768KB tagged h exchange
  char* yT = (char*)d_ws + HT_BYTES;      // 768KB tagged y0 ring
  // zero ALL tags each replay (tags count up from 1; memset-0 can never match)
  hipMemsetAsync(d_ws, 0, HT_BYTES + YT_BYTES, stream);

  dim3 grid(GROUP * 8), block(256);
  gru_fused<<<grid, block, 0, stream>>>(x, enc, WihF, WhhF, bihF, bhhF,
                                        WihB, WhhB, bihB, bhhB, out, hT, yT);
}